// Round 1
// baseline (416.486 us; speedup 1.0000x reference)
//
#include <hip/hip_runtime.h>
#include <hip/hip_bf16.h>

#define N_NODES 10000
#define N_EDGES 640000
#define TOT_E   (N_EDGES + N_NODES)
#define HID     128
#define NEG_SLOPE 0.2f
#define N_ACT   4096
#define CH      128   // agg LDS chunk (max degree ~100 expected, chunking handles any)

// ---------------- CSR build ----------------

__global__ void zero_k(int* __restrict__ offs, int* __restrict__ cursor) {
    int i = blockIdx.x * blockDim.x + threadIdx.x;
    if (i <= N_NODES) offs[i] = 0;
    if (i <  N_NODES) cursor[i] = 0;
}

__global__ void count_k(const int* __restrict__ ei, int* __restrict__ cnt) {
    int e = blockIdx.x * blockDim.x + threadIdx.x;
    if (e >= TOT_E) return;
    int dst = (e < N_EDGES) ? ei[N_EDGES + e] : (e - N_EDGES);
    atomicAdd(&cnt[dst], 1);
}

__global__ __launch_bounds__(256) void scan_k(int* __restrict__ offs) {
    __shared__ int partial[256];
    int t = threadIdx.x;
    int base = t * 40;                 // 256*40 = 10240 >= 10000
    int sum = 0;
    for (int i = 0; i < 40; i++) {
        int idx = base + i;
        if (idx < N_NODES) sum += offs[idx];
    }
    partial[t] = sum;
    __syncthreads();
    for (int off = 1; off < 256; off <<= 1) {
        int v = (t >= off) ? partial[t - off] : 0;
        __syncthreads();
        partial[t] += v;
        __syncthreads();
    }
    int run = partial[t] - sum;        // exclusive prefix for this thread's chunk
    for (int i = 0; i < 40; i++) {
        int idx = base + i;
        if (idx < N_NODES) {
            int c = offs[idx];
            offs[idx] = run;
            run += c;
        }
    }
    if (t == 255) offs[N_NODES] = partial[255];
}

__global__ void scatter_k(const int* __restrict__ ei, const int* __restrict__ offs,
                          int* __restrict__ cursor, int* __restrict__ csr) {
    int e = blockIdx.x * blockDim.x + threadIdx.x;
    if (e >= TOT_E) return;
    int src, dst;
    if (e < N_EDGES) { src = ei[e]; dst = ei[N_EDGES + e]; }
    else             { src = e - N_EDGES; dst = src; }
    int p = atomicAdd(&cursor[dst], 1);
    csr[offs[dst] + p] = src;
}

// ---------------- z = h @ W  (fp32, LDS-staged W, 4x4 register tile) ----------------

__global__ __launch_bounds__(256) void gemm_k(const float* __restrict__ A,
                                              const float* __restrict__ W,
                                              float* __restrict__ Z) {
    __shared__ float Wl[HID * HID];    // 64 KB
    int t = threadIdx.x;
    {
        const float4* W4 = (const float4*)W;
        float4* Wl4 = (float4*)Wl;
        for (int i = t; i < HID * HID / 4; i += 256) Wl4[i] = W4[i];
    }
    __syncthreads();
    int tx = t & 31;                   // 32 col-groups of 4 cols
    int ty = t >> 5;                   // 8 row-groups of 4 rows -> 32 rows/block
    int row0 = blockIdx.x * 32 + ty * 4;
    float acc[4][4] = {{0.f}};
    for (int k = 0; k < HID; k += 4) {
        float ar[4][4];
#pragma unroll
        for (int r = 0; r < 4; r++) {
            int row = row0 + r;
            float4 av = (row < N_NODES) ? *(const float4*)&A[row * HID + k]
                                        : make_float4(0.f, 0.f, 0.f, 0.f);
            ar[r][0] = av.x; ar[r][1] = av.y; ar[r][2] = av.z; ar[r][3] = av.w;
        }
#pragma unroll
        for (int kk = 0; kk < 4; kk++) {
            float4 wv = *(const float4*)&Wl[(k + kk) * HID + tx * 4];
#pragma unroll
            for (int r = 0; r < 4; r++) {
                acc[r][0] = fmaf(ar[r][kk], wv.x, acc[r][0]);
                acc[r][1] = fmaf(ar[r][kk], wv.y, acc[r][1]);
                acc[r][2] = fmaf(ar[r][kk], wv.z, acc[r][2]);
                acc[r][3] = fmaf(ar[r][kk], wv.w, acc[r][3]);
            }
        }
    }
    for (int r = 0; r < 4; r++) {
        int row = row0 + r;
        if (row < N_NODES)
            *(float4*)&Z[row * HID + tx * 4] =
                make_float4(acc[r][0], acc[r][1], acc[r][2], acc[r][3]);
    }
}

// ---------------- per-node attention scalars: zs = z@a_src, zd = z@a_dst ----------------

__global__ __launch_bounds__(64) void dots_k(const float* __restrict__ z,
                                             const float* __restrict__ as,
                                             const float* __restrict__ ad,
                                             float* __restrict__ zs, float* __restrict__ zd) {
    int n = blockIdx.x, l = threadIdx.x;
    float z0 = z[n * HID + l];
    float z1 = z[n * HID + 64 + l];
    float s = z0 * as[l] + z1 * as[64 + l];
    float d = z0 * ad[l] + z1 * ad[64 + l];
    for (int off = 32; off; off >>= 1) {
        s += __shfl_down(s, off, 64);
        d += __shfl_down(d, off, 64);
    }
    if (l == 0) { zs[n] = s; zd[n] = d; }
}

// ---------------- edge-softmax + aggregate: one wave per node ----------------

__global__ __launch_bounds__(64) void agg_k(const float* __restrict__ z,
                                            const float* __restrict__ zs,
                                            const float* __restrict__ zd,
                                            const int* __restrict__ offs,
                                            const int* __restrict__ csr,
                                            const float* __restrict__ b,
                                            float* __restrict__ hout) {
    int n = blockIdx.x;
    int lane = threadIdx.x;
    int o0 = offs[n], o1 = offs[n + 1];
    int deg = o1 - o0;                 // >= 1 (self loop)
    float zdn = zd[n];

    // pass 1: max over incoming edges
    float m = -3.4e38f;
    for (int j = lane; j < deg; j += 64) {
        int s = csr[o0 + j];
        float e = zs[s] + zdn;
        e = e > 0.f ? e : NEG_SLOPE * e;
        m = fmaxf(m, e);
    }
    for (int off = 32; off; off >>= 1) m = fmaxf(m, __shfl_xor(m, off, 64));

    __shared__ float ex_s[CH];
    __shared__ int   sr_s[CH];
    float acc0 = 0.f, acc1 = 0.f, denom = 0.f;
    for (int base = 0; base < deg; base += CH) {
        int cnt = min(CH, deg - base);
        for (int j = lane; j < cnt; j += 64) {
            int s = csr[o0 + base + j];
            float e = zs[s] + zdn;
            e = e > 0.f ? e : NEG_SLOPE * e;
            ex_s[j] = expf(e - m);
            sr_s[j] = s;
        }
        __syncthreads();
        for (int j = 0; j < cnt; j++) {
            float ex = ex_s[j];
            int s = sr_s[j];
            denom += ex;               // every lane sums full denom (no reduce needed)
            acc0 = fmaf(ex, z[s * HID + lane], acc0);
            acc1 = fmaf(ex, z[s * HID + 64 + lane], acc1);
        }
        __syncthreads();
    }
    float inv = 1.0f / denom;
    float v0 = acc0 * inv + b[lane];
    float v1 = acc1 * inv + b[64 + lane];
    hout[n * HID + lane]      = v0 > 0.f ? v0 : 0.f;
    hout[n * HID + 64 + lane] = v1 > 0.f ? v1 : 0.f;
}

// ---------------- action scoring MLP ----------------

__global__ __launch_bounds__(128) void score_k(const float* __restrict__ h,
                                               const int* __restrict__ asrc,
                                               const int* __restrict__ adst,
                                               const int* __restrict__ atype,
                                               const float* __restrict__ W1,
                                               const float* __restrict__ b1,
                                               const float* __restrict__ W2,
                                               const float* __restrict__ b2,
                                               float* __restrict__ out) {
    int a = blockIdx.x, t = threadIdx.x;
    __shared__ float hs[HID], hd[HID];
    int s = asrc[a], d = adst[a];
    hs[t] = h[s * HID + t];
    hd[t] = h[d * HID + t];
    __syncthreads();
    float acc = b1[t];
    for (int k = 0; k < HID; k++) acc = fmaf(hs[k], W1[k * HID + t], acc);
    for (int k = 0; k < HID; k++) acc = fmaf(hd[k], W1[(HID + k) * HID + t], acc);
    acc = fmaf((float)atype[a], W1[2 * HID * HID + t], acc);
    acc = acc > 0.f ? acc : 0.f;
    float v = acc * W2[t];
    for (int off = 32; off; off >>= 1) v += __shfl_down(v, off, 64);
    __shared__ float red[2];
    if ((t & 63) == 0) red[t >> 6] = v;
    __syncthreads();
    if (t == 0) out[a] = red[0] + red[1] + b2[0];
}

// ---------------- launch ----------------

extern "C" void kernel_launch(void* const* d_in, const int* in_sizes, int n_in,
                              void* d_out, int out_size, void* d_ws, size_t ws_size,
                              hipStream_t stream) {
    const float* x   = (const float*)d_in[0];
    const int* ei    = (const int*)d_in[1];
    const int* asrc  = (const int*)d_in[2];
    const int* adst  = (const int*)d_in[3];
    const int* atype = (const int*)d_in[4];
    const float* gW  = (const float*)d_in[5];
    const float* gas = (const float*)d_in[6];
    const float* gad = (const float*)d_in[7];
    const float* gb  = (const float*)d_in[8];
    const float* W1  = (const float*)d_in[9];
    const float* b1  = (const float*)d_in[10];
    const float* W2  = (const float*)d_in[11];
    const float* b2  = (const float*)d_in[12];
    float* out = (float*)d_out;

    float* z  = (float*)d_ws;              // 1,280,000 f32
    float* hA = z  + N_NODES * HID;        // 1,280,000
    float* hB = hA + N_NODES * HID;        // 1,280,000
    float* zs = hB + N_NODES * HID;        // 10,000
    float* zd = zs + N_NODES;              // 10,000
    int* offs   = (int*)(zd + N_NODES);    // 10,001
    int* cursor = offs + (N_NODES + 1);    // 10,000
    int* csr    = cursor + N_NODES;        // 650,000
    // total ~18.2 MB

    zero_k<<<(N_NODES + 256) / 256, 256, 0, stream>>>(offs, cursor);
    count_k<<<(TOT_E + 255) / 256, 256, 0, stream>>>(ei, offs);
    scan_k<<<1, 256, 0, stream>>>(offs);
    scatter_k<<<(TOT_E + 255) / 256, 256, 0, stream>>>(ei, offs, cursor, csr);

    const float* hin = x;
    float* bufs[3] = { hA, hB, hA };
    for (int l = 0; l < 3; l++) {
        gemm_k<<<(N_NODES + 31) / 32, 256, 0, stream>>>(hin, gW + l * HID * HID, z);
        dots_k<<<N_NODES, 64, 0, stream>>>(z, gas + l * HID, gad + l * HID, zs, zd);
        agg_k<<<N_NODES, 64, 0, stream>>>(z, zs, zd, offs, csr, gb + l * HID, bufs[l]);
        hin = bufs[l];
    }
    score_k<<<N_ACT, 128, 0, stream>>>(hin, asrc, adst, atype, W1, b1, W2, b2, out);
}

// Round 2
// 315.491 us; speedup vs baseline: 1.3201x; 1.3201x over previous
//
#include <hip/hip_runtime.h>
#include <hip/hip_bf16.h>

#define N_NODES 10000
#define N_EDGES 640000
#define TOT_E   (N_EDGES + N_NODES)
#define HID     128
#define NEG_SLOPE 0.2f
#define N_ACT   4096
#define CH      128   // agg LDS chunk

// ---- bucket counting-sort CSR build ----
#define NBKT   64
#define NPB    157                       // ceil(10000/64) nodes per bucket
#define CAP    16384                     // per-bucket partition capacity (mean ~10.2K)
#define P1_EPB 4096                      // edges per pass-1 block
#define P1_EPT 16                        // edges per thread (256 thr)
#define P1_BLOCKS ((TOT_E + P1_EPB - 1) / P1_EPB)

__global__ void zero_bcur_k(int* __restrict__ bcur) {
    if (threadIdx.x < NBKT) bcur[threadIdx.x] = 0;
}

// Pass 1: partition edges into 64 dst-range buckets, packed (dst<<16)|src.
__global__ __launch_bounds__(256) void part1_k(const int* __restrict__ ei,
                                               unsigned* __restrict__ bpart,
                                               int* __restrict__ bcur) {
    __shared__ int hist[NBKT];
    __shared__ int lofs[NBKT];
    __shared__ int gbase[NBKT];
    __shared__ unsigned stage[P1_EPB];
    __shared__ unsigned char bkt_of[P1_EPB];
    int t = threadIdx.x;
    if (t < NBKT) hist[t] = 0;
    __syncthreads();

    unsigned pk[P1_EPT];
    int bk[P1_EPT];
    int e0 = blockIdx.x * P1_EPB;
#pragma unroll
    for (int i = 0; i < P1_EPT; i++) {
        int e = e0 + i * 256 + t;
        if (e < TOT_E) {
            int src, dst;
            if (e < N_EDGES) { src = ei[e]; dst = ei[N_EDGES + e]; }
            else             { src = e - N_EDGES; dst = src; }
            pk[i] = ((unsigned)dst << 16) | (unsigned)src;
            bk[i] = dst / NPB;
            atomicAdd(&hist[bk[i]], 1);
        } else bk[i] = -1;
    }
    __syncthreads();
    if (t < 64) {
        int v = hist[t];
        int s = v;
        for (int o = 1; o < 64; o <<= 1) {
            int u = __shfl_up(s, o, 64);
            if (t >= o) s += u;
        }
        lofs[t] = s - v;                       // exclusive local offset
        gbase[t] = atomicAdd(&bcur[t], v);     // reserve global range (64 atomics/block)
        hist[t] = 0;                           // reuse as cursor
    }
    __syncthreads();
#pragma unroll
    for (int i = 0; i < P1_EPT; i++) {
        if (bk[i] >= 0) {
            int p = atomicAdd(&hist[bk[i]], 1);
            int slot = lofs[bk[i]] + p;
            stage[slot] = pk[i];
            bkt_of[slot] = (unsigned char)bk[i];
        }
    }
    __syncthreads();
    int nv = min(P1_EPB, TOT_E - e0);
    for (int s = t; s < nv; s += 256) {
        int b = bkt_of[s];
        bpart[b * CAP + gbase[b] + (s - lofs[b])] = stage[s];
    }
}

// Pass 2: one block per bucket -> node histogram, offs[], scatter csr (XCD-local).
__global__ __launch_bounds__(256) void part2_k(const unsigned* __restrict__ bpart,
                                               const int* __restrict__ bcur,
                                               int* __restrict__ csr,
                                               int* __restrict__ offs) {
    __shared__ int nhist[NPB];
    __shared__ int bstart_s;
    int b = blockIdx.x, t = threadIdx.x;
    if (t < 64) {
        int v = bcur[t];
        int s = v;
        for (int o = 1; o < 64; o <<= 1) {
            int u = __shfl_up(s, o, 64);
            if (t >= o) s += u;
        }
        if (t == b) bstart_s = s - v;                   // bucket's csr start
        if (b == 0 && t == 63) offs[N_NODES] = s;       // total = TOT_E
    }
    for (int i = t; i < NPB; i += 256) nhist[i] = 0;
    __syncthreads();

    int cnt = bcur[b];
    int n0 = b * NPB;
    int nn = min(NPB, N_NODES - n0);
    const unsigned* bp = bpart + b * CAP;

    for (int i = t; i < cnt; i += 256) {
        int dst = bp[i] >> 16;
        atomicAdd(&nhist[dst - n0], 1);
    }
    __syncthreads();
    // wave-0 scan of nhist over nn entries -> node offsets + offs[]
    if (t < 64) {
        int carry = bstart_s;
        for (int c = 0; c < (NPB + 63) / 64; c++) {
            int idx = c * 64 + t;
            int v = (idx < nn) ? nhist[idx] : 0;
            int s = v;
            for (int o = 1; o < 64; o <<= 1) {
                int u = __shfl_up(s, o, 64);
                if (t >= o) s += u;
            }
            if (idx < nn) {
                nhist[idx] = carry + s - v;
                offs[n0 + idx] = carry + s - v;
            }
            carry += __shfl(s, 63, 64);
        }
    }
    __syncthreads();
    for (int i = t; i < cnt; i += 256) {
        unsigned pk = bp[i];
        int dst = pk >> 16, src = pk & 0xFFFF;
        int p = atomicAdd(&nhist[dst - n0], 1);
        csr[p] = src;
    }
}

// ---------------- z = h @ W  (fp32, LDS-staged W, 4x4 register tile) ----------------

__global__ __launch_bounds__(256) void gemm_k(const float* __restrict__ A,
                                              const float* __restrict__ W,
                                              float* __restrict__ Z) {
    __shared__ float Wl[HID * HID];
    int t = threadIdx.x;
    {
        const float4* W4 = (const float4*)W;
        float4* Wl4 = (float4*)Wl;
        for (int i = t; i < HID * HID / 4; i += 256) Wl4[i] = W4[i];
    }
    __syncthreads();
    int tx = t & 31;
    int ty = t >> 5;
    int row0 = blockIdx.x * 32 + ty * 4;
    float acc[4][4] = {{0.f}};
    for (int k = 0; k < HID; k += 4) {
        float ar[4][4];
#pragma unroll
        for (int r = 0; r < 4; r++) {
            int row = row0 + r;
            float4 av = (row < N_NODES) ? *(const float4*)&A[row * HID + k]
                                        : make_float4(0.f, 0.f, 0.f, 0.f);
            ar[r][0] = av.x; ar[r][1] = av.y; ar[r][2] = av.z; ar[r][3] = av.w;
        }
#pragma unroll
        for (int kk = 0; kk < 4; kk++) {
            float4 wv = *(const float4*)&Wl[(k + kk) * HID + tx * 4];
#pragma unroll
            for (int r = 0; r < 4; r++) {
                acc[r][0] = fmaf(ar[r][kk], wv.x, acc[r][0]);
                acc[r][1] = fmaf(ar[r][kk], wv.y, acc[r][1]);
                acc[r][2] = fmaf(ar[r][kk], wv.z, acc[r][2]);
                acc[r][3] = fmaf(ar[r][kk], wv.w, acc[r][3]);
            }
        }
    }
    for (int r = 0; r < 4; r++) {
        int row = row0 + r;
        if (row < N_NODES)
            *(float4*)&Z[row * HID + tx * 4] =
                make_float4(acc[r][0], acc[r][1], acc[r][2], acc[r][3]);
    }
}

// ---------------- per-node attention scalars ----------------

__global__ __launch_bounds__(64) void dots_k(const float* __restrict__ z,
                                             const float* __restrict__ as,
                                             const float* __restrict__ ad,
                                             float* __restrict__ zs, float* __restrict__ zd) {
    int n = blockIdx.x, l = threadIdx.x;
    float z0 = z[n * HID + l];
    float z1 = z[n * HID + 64 + l];
    float s = z0 * as[l] + z1 * as[64 + l];
    float d = z0 * ad[l] + z1 * ad[64 + l];
    for (int off = 32; off; off >>= 1) {
        s += __shfl_down(s, off, 64);
        d += __shfl_down(d, off, 64);
    }
    if (l == 0) { zs[n] = s; zd[n] = d; }
}

// ---------------- edge-softmax + aggregate: one wave per node ----------------

__global__ __launch_bounds__(64) void agg_k(const float* __restrict__ z,
                                            const float* __restrict__ zs,
                                            const float* __restrict__ zd,
                                            const int* __restrict__ offs,
                                            const int* __restrict__ csr,
                                            const float* __restrict__ b,
                                            float* __restrict__ hout) {
    int n = blockIdx.x;
    int lane = threadIdx.x;
    int o0 = offs[n], o1 = offs[n + 1];
    int deg = o1 - o0;
    float zdn = zd[n];

    float m = -3.4e38f;
    for (int j = lane; j < deg; j += 64) {
        int s = csr[o0 + j];
        float e = zs[s] + zdn;
        e = e > 0.f ? e : NEG_SLOPE * e;
        m = fmaxf(m, e);
    }
    for (int off = 32; off; off >>= 1) m = fmaxf(m, __shfl_xor(m, off, 64));

    __shared__ float ex_s[CH];
    __shared__ int   sr_s[CH];
    float acc0 = 0.f, acc1 = 0.f, denom = 0.f;
    for (int base = 0; base < deg; base += CH) {
        int cnt = min(CH, deg - base);
        for (int j = lane; j < cnt; j += 64) {
            int s = csr[o0 + base + j];
            float e = zs[s] + zdn;
            e = e > 0.f ? e : NEG_SLOPE * e;
            ex_s[j] = expf(e - m);
            sr_s[j] = s;
        }
        __syncthreads();
        for (int j = 0; j < cnt; j++) {
            float ex = ex_s[j];
            int s = sr_s[j];
            denom += ex;
            acc0 = fmaf(ex, z[s * HID + lane], acc0);
            acc1 = fmaf(ex, z[s * HID + 64 + lane], acc1);
        }
        __syncthreads();
    }
    float inv = 1.0f / denom;
    float v0 = acc0 * inv + b[lane];
    float v1 = acc1 * inv + b[64 + lane];
    hout[n * HID + lane]      = v0 > 0.f ? v0 : 0.f;
    hout[n * HID + 64 + lane] = v1 > 0.f ? v1 : 0.f;
}

// ---------------- action scoring MLP ----------------

__global__ __launch_bounds__(128) void score_k(const float* __restrict__ h,
                                               const int* __restrict__ asrc,
                                               const int* __restrict__ adst,
                                               const int* __restrict__ atype,
                                               const float* __restrict__ W1,
                                               const float* __restrict__ b1,
                                               const float* __restrict__ W2,
                                               const float* __restrict__ b2,
                                               float* __restrict__ out) {
    int a = blockIdx.x, t = threadIdx.x;
    __shared__ float hs[HID], hd[HID];
    int s = asrc[a], d = adst[a];
    hs[t] = h[s * HID + t];
    hd[t] = h[d * HID + t];
    __syncthreads();
    float acc = b1[t];
    for (int k = 0; k < HID; k++) acc = fmaf(hs[k], W1[k * HID + t], acc);
    for (int k = 0; k < HID; k++) acc = fmaf(hd[k], W1[(HID + k) * HID + t], acc);
    acc = fmaf((float)atype[a], W1[2 * HID * HID + t], acc);
    acc = acc > 0.f ? acc : 0.f;
    float v = acc * W2[t];
    for (int off = 32; off; off >>= 1) v += __shfl_down(v, off, 64);
    __shared__ float red[2];
    if ((t & 63) == 0) red[t >> 6] = v;
    __syncthreads();
    if (t == 0) out[a] = red[0] + red[1] + b2[0];
}

// ---------------- launch ----------------

extern "C" void kernel_launch(void* const* d_in, const int* in_sizes, int n_in,
                              void* d_out, int out_size, void* d_ws, size_t ws_size,
                              hipStream_t stream) {
    const float* x   = (const float*)d_in[0];
    const int* ei    = (const int*)d_in[1];
    const int* asrc  = (const int*)d_in[2];
    const int* adst  = (const int*)d_in[3];
    const int* atype = (const int*)d_in[4];
    const float* gW  = (const float*)d_in[5];
    const float* gas = (const float*)d_in[6];
    const float* gad = (const float*)d_in[7];
    const float* gb  = (const float*)d_in[8];
    const float* W1  = (const float*)d_in[9];
    const float* b1  = (const float*)d_in[10];
    const float* W2  = (const float*)d_in[11];
    const float* b2  = (const float*)d_in[12];
    float* out = (float*)d_out;

    float* z  = (float*)d_ws;              // 1,280,000 f32  (aliased by bpart during CSR build)
    float* hA = z  + N_NODES * HID;
    float* hB = hA + N_NODES * HID;
    float* zs = hB + N_NODES * HID;
    float* zd = zs + N_NODES;
    int* offs = (int*)(zd + N_NODES);      // 10,001
    int* csr  = offs + (N_NODES + 1);      // 650,000
    int* bcur = csr + TOT_E;               // 64
    unsigned* bpart = (unsigned*)z;        // 64*16384 = 1,048,576 u32 (4 MB) < z's 5.12 MB

    zero_bcur_k<<<1, 64, 0, stream>>>(bcur);
    part1_k<<<P1_BLOCKS, 256, 0, stream>>>(ei, bpart, bcur);
    part2_k<<<NBKT, 256, 0, stream>>>(bpart, bcur, csr, offs);

    const float* hin = x;
    float* bufs[3] = { hA, hB, hA };
    for (int l = 0; l < 3; l++) {
        gemm_k<<<(N_NODES + 31) / 32, 256, 0, stream>>>(hin, gW + l * HID * HID, z);
        dots_k<<<N_NODES, 64, 0, stream>>>(z, gas + l * HID, gad + l * HID, zs, zd);
        agg_k<<<N_NODES, 64, 0, stream>>>(z, zs, zd, offs, csr, gb + l * HID, bufs[l]);
        hin = bufs[l];
    }
    score_k<<<N_ACT, 128, 0, stream>>>(hin, asrc, adst, atype, W1, b1, W2, b2, out);
}

// Round 3
// 285.370 us; speedup vs baseline: 1.4595x; 1.1056x over previous
//
#include <hip/hip_runtime.h>
#include <hip/hip_bf16.h>
#include <hip/hip_fp16.h>

#define N_NODES 10000
#define N_EDGES 640000
#define TOT_E   (N_EDGES + N_NODES)
#define HID     128
#define NEG_SLOPE 0.2f
#define N_ACT   4096
#define CH      128   // agg LDS chunk per wave

// ---- bucket counting-sort CSR build ----
#define NBKT   64
#define NPB    157
#define CAP    16384
#define P1_EPB 4096
#define P1_EPT 16
#define P1_BLOCKS ((TOT_E + P1_EPB - 1) / P1_EPB)

__global__ void zero_bcur_k(int* __restrict__ bcur) {
    if (threadIdx.x < NBKT) bcur[threadIdx.x] = 0;
}

__global__ __launch_bounds__(256) void part1_k(const int* __restrict__ ei,
                                               unsigned* __restrict__ bpart,
                                               int* __restrict__ bcur) {
    __shared__ int hist[NBKT];
    __shared__ int lofs[NBKT];
    __shared__ int gbase[NBKT];
    __shared__ unsigned stage[P1_EPB];
    __shared__ unsigned char bkt_of[P1_EPB];
    int t = threadIdx.x;
    if (t < NBKT) hist[t] = 0;
    __syncthreads();

    unsigned pk[P1_EPT];
    int bk[P1_EPT];
    int e0 = blockIdx.x * P1_EPB;
#pragma unroll
    for (int i = 0; i < P1_EPT; i++) {
        int e = e0 + i * 256 + t;
        if (e < TOT_E) {
            int src, dst;
            if (e < N_EDGES) { src = ei[e]; dst = ei[N_EDGES + e]; }
            else             { src = e - N_EDGES; dst = src; }
            pk[i] = ((unsigned)dst << 16) | (unsigned)src;
            bk[i] = dst / NPB;
            atomicAdd(&hist[bk[i]], 1);
        } else bk[i] = -1;
    }
    __syncthreads();
    if (t < 64) {
        int v = hist[t];
        int s = v;
        for (int o = 1; o < 64; o <<= 1) {
            int u = __shfl_up(s, o, 64);
            if (t >= o) s += u;
        }
        lofs[t] = s - v;
        gbase[t] = atomicAdd(&bcur[t], v);
        hist[t] = 0;
    }
    __syncthreads();
#pragma unroll
    for (int i = 0; i < P1_EPT; i++) {
        if (bk[i] >= 0) {
            int p = atomicAdd(&hist[bk[i]], 1);
            int slot = lofs[bk[i]] + p;
            stage[slot] = pk[i];
            bkt_of[slot] = (unsigned char)bk[i];
        }
    }
    __syncthreads();
    int nv = min(P1_EPB, TOT_E - e0);
    for (int s = t; s < nv; s += 256) {
        int b = bkt_of[s];
        bpart[b * CAP + gbase[b] + (s - lofs[b])] = stage[s];
    }
}

__global__ __launch_bounds__(256) void part2_k(const unsigned* __restrict__ bpart,
                                               const int* __restrict__ bcur,
                                               int* __restrict__ csr,
                                               int* __restrict__ offs) {
    __shared__ int nhist[NPB];
    __shared__ int bstart_s;
    int b = blockIdx.x, t = threadIdx.x;
    if (t < 64) {
        int v = bcur[t];
        int s = v;
        for (int o = 1; o < 64; o <<= 1) {
            int u = __shfl_up(s, o, 64);
            if (t >= o) s += u;
        }
        if (t == b) bstart_s = s - v;
        if (b == 0 && t == 63) offs[N_NODES] = s;
    }
    for (int i = t; i < NPB; i += 256) nhist[i] = 0;
    __syncthreads();

    int cnt = bcur[b];
    int n0 = b * NPB;
    int nn = min(NPB, N_NODES - n0);
    const unsigned* bp = bpart + b * CAP;

    for (int i = t; i < cnt; i += 256) {
        int dst = bp[i] >> 16;
        atomicAdd(&nhist[dst - n0], 1);
    }
    __syncthreads();
    if (t < 64) {
        int carry = bstart_s;
        for (int c = 0; c < (NPB + 63) / 64; c++) {
            int idx = c * 64 + t;
            int v = (idx < nn) ? nhist[idx] : 0;
            int s = v;
            for (int o = 1; o < 64; o <<= 1) {
                int u = __shfl_up(s, o, 64);
                if (t >= o) s += u;
            }
            if (idx < nn) {
                nhist[idx] = carry + s - v;
                offs[n0 + idx] = carry + s - v;
            }
            carry += __shfl(s, 63, 64);
        }
    }
    __syncthreads();
    for (int i = t; i < cnt; i += 256) {
        unsigned pk = bp[i];
        int dst = pk >> 16, src = pk & 0xFFFF;
        int p = atomicAdd(&nhist[dst - n0], 1);
        csr[p] = src;
    }
}

// -------- gemm + fused attention dots: z16 = fp16(h@W), zs = z@a_src, zd = z@a_dst --------

__global__ __launch_bounds__(256) void gemm_k(const float* __restrict__ A,
                                              const float* __restrict__ W,
                                              const float* __restrict__ avs,
                                              const float* __restrict__ avd,
                                              __half* __restrict__ z16,
                                              float* __restrict__ zs,
                                              float* __restrict__ zd) {
    __shared__ float Wl[HID * HID];
    int t = threadIdx.x;
    {
        const float4* W4 = (const float4*)W;
        float4* Wl4 = (float4*)Wl;
        for (int i = t; i < HID * HID / 4; i += 256) Wl4[i] = W4[i];
    }
    __syncthreads();
    int tx = t & 31;
    int ty = t >> 5;
    int row0 = blockIdx.x * 32 + ty * 4;
    float acc[4][4] = {{0.f}};
    for (int k = 0; k < HID; k += 4) {
        float ar[4][4];
#pragma unroll
        for (int r = 0; r < 4; r++) {
            int row = row0 + r;
            float4 av = (row < N_NODES) ? *(const float4*)&A[row * HID + k]
                                        : make_float4(0.f, 0.f, 0.f, 0.f);
            ar[r][0] = av.x; ar[r][1] = av.y; ar[r][2] = av.z; ar[r][3] = av.w;
        }
#pragma unroll
        for (int kk = 0; kk < 4; kk++) {
            float4 wv = *(const float4*)&Wl[(k + kk) * HID + tx * 4];
#pragma unroll
            for (int r = 0; r < 4; r++) {
                acc[r][0] = fmaf(ar[r][kk], wv.x, acc[r][0]);
                acc[r][1] = fmaf(ar[r][kk], wv.y, acc[r][1]);
                acc[r][2] = fmaf(ar[r][kk], wv.z, acc[r][2]);
                acc[r][3] = fmaf(ar[r][kk], wv.w, acc[r][3]);
            }
        }
    }
    // epilogue: z16 store + fused per-row dots
    float4 asv = *(const float4*)&avs[tx * 4];
    float4 adv = *(const float4*)&avd[tx * 4];
#pragma unroll
    for (int r = 0; r < 4; r++) {
        int row = row0 + r;
        if (row < N_NODES) {
            *(__half2*)&z16[row * HID + tx * 4]     = __floats2half2_rn(acc[r][0], acc[r][1]);
            *(__half2*)&z16[row * HID + tx * 4 + 2] = __floats2half2_rn(acc[r][2], acc[r][3]);
        }
        float ps = acc[r][0] * asv.x + acc[r][1] * asv.y + acc[r][2] * asv.z + acc[r][3] * asv.w;
        float pd = acc[r][0] * adv.x + acc[r][1] * adv.y + acc[r][2] * adv.z + acc[r][3] * adv.w;
#pragma unroll
        for (int o = 1; o < 32; o <<= 1) {
            ps += __shfl_xor(ps, o, 64);
            pd += __shfl_xor(pd, o, 64);
        }
        if (tx == 0 && row < N_NODES) { zs[row] = ps; zd[row] = pd; }
    }
}

// -------- edge-softmax + aggregate: 4 nodes/block, one wave per node, no block barriers --------

__global__ __launch_bounds__(256) void agg_k(const __half* __restrict__ z16,
                                             const float* __restrict__ zs,
                                             const float* __restrict__ zd,
                                             const int* __restrict__ offs,
                                             const int* __restrict__ csr,
                                             const float* __restrict__ b,
                                             float* __restrict__ hout) {
    __shared__ float ex_s[4][CH];
    __shared__ int   sr_s[4][CH];
    int t = threadIdx.x;
    int w = t >> 6;                     // wave id 0..3
    int lane = t & 63;
    int n = blockIdx.x * 4 + w;
    if (n >= N_NODES) return;
    int o0 = offs[n], o1 = offs[n + 1];
    int deg = o1 - o0;
    float zdn = zd[n];

    // pass 1: max
    float m = -3.4e38f;
    for (int j = lane; j < deg; j += 64) {
        int s = csr[o0 + j];
        float e = zs[s] + zdn;
        e = e > 0.f ? e : NEG_SLOPE * e;
        m = fmaxf(m, e);
    }
#pragma unroll
    for (int o = 32; o; o >>= 1) m = fmaxf(m, __shfl_xor(m, o, 64));

    float* ex_w = ex_s[w];
    int*   sr_w = sr_s[w];
    const __half2* z2 = (const __half2*)z16;
    float accx = 0.f, accy = 0.f, denom = 0.f;
    for (int base = 0; base < deg; base += CH) {
        int cnt = min(CH, deg - base);
        for (int j = lane; j < cnt; j += 64) {
            int s = csr[o0 + base + j];
            float e = zs[s] + zdn;
            e = e > 0.f ? e : NEG_SLOPE * e;
            ex_w[j] = __expf(e - m);
            sr_w[j] = s;
        }
        __threadfence_block();          // order per-wave LDS writes before reads (in-wave)
        for (int j = 0; j < cnt; j++) {
            float ex = ex_w[j];
            int s = sr_w[j];
            denom += ex;
            float2 vf = __half22float2(z2[s * 64 + lane]);
            accx = fmaf(ex, vf.x, accx);
            accy = fmaf(ex, vf.y, accy);
        }
        __threadfence_block();
    }
    float inv = 1.0f / denom;
    float2 bv = *(const float2*)&b[2 * lane];
    float vx = accx * inv + bv.x;
    float vy = accy * inv + bv.y;
    float2 o;
    o.x = vx > 0.f ? vx : 0.f;
    o.y = vy > 0.f ? vy : 0.f;
    *(float2*)&hout[n * HID + 2 * lane] = o;
}

// -------- action scoring MLP: 8 actions/block, W1 streamed once per block --------

#define ACT_PB 8

__global__ __launch_bounds__(256) void score_k(const float* __restrict__ h,
                                               const int* __restrict__ asrc,
                                               const int* __restrict__ adst,
                                               const int* __restrict__ atype,
                                               const float* __restrict__ W1,
                                               const float* __restrict__ b1,
                                               const float* __restrict__ W2,
                                               const float* __restrict__ b2,
                                               float* __restrict__ out) {
    __shared__ float feat[ACT_PB][264];     // 257 used, padded
    int t = threadIdx.x;
    int a0 = blockIdx.x * ACT_PB;
    for (int idx = t; idx < ACT_PB * 256; idx += 256) {
        int a = idx >> 8, c = idx & 255;
        int node = (c < 128) ? asrc[a0 + a] : adst[a0 + a];
        feat[a][c] = h[node * HID + (c & 127)];
    }
    if (t < ACT_PB) feat[t][256] = (float)atype[a0 + t];
    __syncthreads();

    int cg = t & 31;                        // 4 cols each
    int ar = t >> 5;                        // action 0..7
    float acc0, acc1, acc2, acc3;
    {
        float4 bv = *(const float4*)&b1[cg * 4];
        acc0 = bv.x; acc1 = bv.y; acc2 = bv.z; acc3 = bv.w;
    }
    const float* fa = feat[ar];
    for (int k = 0; k < 257; k++) {
        float4 wv = *(const float4*)&W1[k * HID + cg * 4];
        float f = fa[k];
        acc0 = fmaf(f, wv.x, acc0);
        acc1 = fmaf(f, wv.y, acc1);
        acc2 = fmaf(f, wv.z, acc2);
        acc3 = fmaf(f, wv.w, acc3);
    }
    acc0 = acc0 > 0.f ? acc0 : 0.f;
    acc1 = acc1 > 0.f ? acc1 : 0.f;
    acc2 = acc2 > 0.f ? acc2 : 0.f;
    acc3 = acc3 > 0.f ? acc3 : 0.f;
    float4 w2v = *(const float4*)&W2[cg * 4];
    float v = acc0 * w2v.x + acc1 * w2v.y + acc2 * w2v.z + acc3 * w2v.w;
#pragma unroll
    for (int o = 1; o < 32; o <<= 1) v += __shfl_xor(v, o, 64);
    if (cg == 0) out[a0 + ar] = v + b2[0];
}

// ---------------- launch ----------------

extern "C" void kernel_launch(void* const* d_in, const int* in_sizes, int n_in,
                              void* d_out, int out_size, void* d_ws, size_t ws_size,
                              hipStream_t stream) {
    const float* x   = (const float*)d_in[0];
    const int* ei    = (const int*)d_in[1];
    const int* asrc  = (const int*)d_in[2];
    const int* adst  = (const int*)d_in[3];
    const int* atype = (const int*)d_in[4];
    const float* gW  = (const float*)d_in[5];
    const float* gas = (const float*)d_in[6];
    const float* gad = (const float*)d_in[7];
    const float* gb  = (const float*)d_in[8];
    const float* W1  = (const float*)d_in[9];
    const float* b1  = (const float*)d_in[10];
    const float* W2  = (const float*)d_in[11];
    const float* b2  = (const float*)d_in[12];
    float* out = (float*)d_out;

    __half* z16 = (__half*)d_ws;                    // 1.28M halves (2.56 MB)
    float* hA = (float*)(z16 + N_NODES * HID);      // 5.12 MB
    float* hB = hA + N_NODES * HID;                 // 5.12 MB
    float* zs = hB + N_NODES * HID;
    float* zd = zs + N_NODES;
    int* offs = (int*)(zd + N_NODES);
    int* csr  = offs + (N_NODES + 1);
    int* bcur = csr + TOT_E;
    unsigned* bpart = (unsigned*)d_ws;              // 4 MB, aliases z16+hA head (CSR build runs first)

    zero_bcur_k<<<1, 64, 0, stream>>>(bcur);
    part1_k<<<P1_BLOCKS, 256, 0, stream>>>(ei, bpart, bcur);
    part2_k<<<NBKT, 256, 0, stream>>>(bpart, bcur, csr, offs);

    const float* hin = x;
    float* bufs[3] = { hA, hB, hA };
    for (int l = 0; l < 3; l++) {
        gemm_k<<<(N_NODES + 31) / 32, 256, 0, stream>>>(hin, gW + l * HID * HID,
                                                        gas + l * HID, gad + l * HID,
                                                        z16, zs, zd);
        agg_k<<<(N_NODES + 3) / 4, 256, 0, stream>>>(z16, zs, zd, offs, csr,
                                                     gb + l * HID, bufs[l]);
        hin = bufs[l];
    }
    score_k<<<N_ACT / ACT_PB, 256, 0, stream>>>(hin, asrc, adst, atype,
                                                W1, b1, W2, b2, out);
}